// Round 1
// baseline (628.074 us; speedup 1.0000x reference)
//
#include <hip/hip_runtime.h>
#include <hip/hip_bf16.h>

typedef unsigned short u16;
typedef __attribute__((ext_vector_type(8))) short bf16x8;
typedef __attribute__((ext_vector_type(4))) float f32x4;
typedef __attribute__((ext_vector_type(8))) u16 u16x8;

#define T_SEQ 2048
#define HID 4096
#define NQ 32
#define NKV 8
#define DH 128
#define WIN 1024

__device__ __forceinline__ u16 f2bf(float f) {
  union { float f; unsigned int u; } v; v.f = f;
  unsigned int u = v.u;
  unsigned int r = (u + 0x7FFFu + ((u >> 16) & 1u)) >> 16;
  return (u16)r;
}

__device__ __forceinline__ void gload16(const void* g, void* l) {
  __builtin_amdgcn_global_load_lds(
      (const __attribute__((address_space(1))) unsigned int*)g,
      (__attribute__((address_space(3))) unsigned int*)l, 16, 0, 0);
}

// ---------------- elementwise f32 -> bf16 ----------------
__global__ __launch_bounds__(256) void f32_to_bf16(const float* __restrict__ in,
                                                   u16* __restrict__ out, int n) {
  int i = (blockIdx.x * 256 + threadIdx.x) * 8;
  if (i >= n) return;
  float4 a = *(const float4*)(in + i);
  float4 b = *(const float4*)(in + i + 4);
  u16x8 r;
  r[0] = f2bf(a.x); r[1] = f2bf(a.y); r[2] = f2bf(a.z); r[3] = f2bf(a.w);
  r[4] = f2bf(b.x); r[5] = f2bf(b.y); r[6] = f2bf(b.z); r[7] = f2bf(b.w);
  *(u16x8*)(out + i) = r;
}

// ---------------- tiled transpose f32 (R x C) -> bf16 (C x R) ----------------
__global__ __launch_bounds__(256) void transpose_f32_to_bf16(const float* __restrict__ in,
                                                             u16* __restrict__ out,
                                                             int R, int C) {
  __shared__ float tile[32][33];
  int c0 = blockIdx.x * 32, r0 = blockIdx.y * 32;
  int tx = threadIdx.x, ty = threadIdx.y;
  for (int i = 0; i < 32; i += 8)
    tile[ty + i][tx] = in[(size_t)(r0 + ty + i) * C + c0 + tx];
  __syncthreads();
  for (int i = 0; i < 32; i += 8)
    out[(size_t)(c0 + ty + i) * R + r0 + tx] = f2bf(tile[tx][ty + i]);
}

// ---------------- GEMM: C(f32 MxN) = A(bf16 MxK row-major) * Bt(bf16 NxK row-major)^T ----
__global__ __launch_bounds__(256) void gemm_bt(const u16* __restrict__ A,
                                               const u16* __restrict__ Bt,
                                               float* __restrict__ C,
                                               int M, int N, int K) {
  __shared__ u16 lsA[128 * 32];  // 8KB, row-major [128][32]
  __shared__ u16 lsB[128 * 32];
  const int tid = threadIdx.x;
  const int lane = tid & 63, w = tid >> 6;
  const int wr = w >> 1, wc = w & 1;
  const int l15 = lane & 15, l4 = lane >> 4;
  const int bm = blockIdx.x * 128, bn = blockIdx.y * 128;
  f32x4 acc[4][4] = {};

  for (int k0 = 0; k0 < K; k0 += 32) {
    for (int c = 0; c < 2; ++c) {
      int off = c * 4096 + tid * 16;       // byte offset within 8KB tile
      int r = off >> 6, cb = off & 63;     // row, byte-in-row (64B rows)
      gload16(A + (size_t)(bm + r) * K + k0 + (cb >> 1),
              (char*)lsA + c * 4096 + w * 1024);
      gload16(Bt + (size_t)(bn + r) * K + k0 + (cb >> 1),
              (char*)lsB + c * 4096 + w * 1024);
    }
    __syncthreads();
    bf16x8 af[4], bfr[4];
    for (int mt = 0; mt < 4; ++mt) {
      int row = wr * 64 + mt * 16 + l15;
      af[mt] = *(const bf16x8*)(lsA + row * 32 + l4 * 8);
    }
    for (int nt = 0; nt < 4; ++nt) {
      int row = wc * 64 + nt * 16 + l15;
      bfr[nt] = *(const bf16x8*)(lsB + row * 32 + l4 * 8);
    }
    for (int mt = 0; mt < 4; ++mt)
      for (int nt = 0; nt < 4; ++nt)
        acc[mt][nt] = __builtin_amdgcn_mfma_f32_16x16x32_bf16(af[mt], bfr[nt], acc[mt][nt], 0, 0, 0);
    __syncthreads();
  }
  for (int mt = 0; mt < 4; ++mt)
    for (int nt = 0; nt < 4; ++nt) {
      int row = bm + wr * 64 + mt * 16 + l4 * 4;
      int col = bn + wc * 64 + nt * 16 + l15;
      float* p = C + (size_t)row * N + col;
      p[0] = acc[mt][nt][0];
      p[(size_t)N] = acc[mt][nt][1];
      p[2 * (size_t)N] = acc[mt][nt][2];
      p[3 * (size_t)N] = acc[mt][nt][3];
    }
}

// ---------------- RMSNorm + RoPE + layout (Q,K row-major per head; V transposed) -------
__global__ __launch_bounds__(256) void rope_kernel(const float* __restrict__ qkv,
                                                   const float* __restrict__ cosb,
                                                   const float* __restrict__ sinb,
                                                   const float* __restrict__ qw,
                                                   const float* __restrict__ kw,
                                                   u16* __restrict__ Qo,
                                                   u16* __restrict__ Ko,
                                                   u16* __restrict__ Vt) {
  int wid = threadIdx.x >> 6, lane = threadIdx.x & 63;
  int item = blockIdx.x * 4 + wid;          // item = t*48 + hid
  int t = item / 48, hid = item % 48;
  const float* x = qkv + (size_t)t * 6144 + hid * 128;
  float x1 = x[lane], x2 = x[lane + 64];
  if (hid < NQ + NKV) {
    float ss = x1 * x1 + x2 * x2;
    for (int off = 32; off; off >>= 1) ss += __shfl_xor(ss, off);
    float inv = rsqrtf(ss * (1.0f / 128.0f) + 1e-6f);
    const float* wn = (hid < NQ) ? qw : kw;
    float n1 = x1 * inv * wn[lane], n2 = x2 * inv * wn[lane + 64];
    float c1 = cosb[t * 128 + lane], s1 = sinb[t * 128 + lane];
    float c2 = cosb[t * 128 + lane + 64], s2 = sinb[t * 128 + lane + 64];
    float o1 = n1 * c1 - n2 * s1;
    float o2 = n2 * c2 + n1 * s2;
    if (hid < NQ) {
      u16* q = Qo + ((size_t)hid * T_SEQ + t) * 128;
      q[lane] = f2bf(o1); q[lane + 64] = f2bf(o2);
    } else {
      int h = hid - NQ;
      u16* k = Ko + ((size_t)h * T_SEQ + t) * 128;
      k[lane] = f2bf(o1); k[lane + 64] = f2bf(o2);
    }
  } else {
    int h = hid - (NQ + NKV);
    Vt[((size_t)h * 128 + lane) * T_SEQ + t] = f2bf(x1);
    Vt[((size_t)h * 128 + lane + 64) * T_SEQ + t] = f2bf(x2);
  }
}

// ---------------- flash attention: 1 wave per (head, 16 q rows) ----------------
__global__ __launch_bounds__(64) void attn_kernel(const u16* __restrict__ Q,
                                                  const u16* __restrict__ Kb,
                                                  const u16* __restrict__ Vt,
                                                  u16* __restrict__ O) {
  __shared__ u16 p_lds[16][40];   // 16 q-rows x 32 k-cols, padded
  const int lane = threadIdx.x;
  const int l15 = lane & 15, l4 = lane >> 4;
  const int q0 = blockIdx.x * 16;
  const int h = blockIdx.y;
  const int kvh = h >> 2;   // GQA: q head h -> kv head h/4

  bf16x8 qf[4];
  const u16* qrow = Q + ((size_t)h * T_SEQ + (q0 + l15)) * 128;
  for (int ks = 0; ks < 4; ++ks)
    qf[ks] = *(const bf16x8*)(qrow + ks * 32 + l4 * 8);

  f32x4 acc[8] = {};
  float m[4], lsum[4];
  for (int i = 0; i < 4; ++i) { m[i] = -1e30f; lsum[i] = 0.f; }

  int kstart = q0 - (WIN - 1); if (kstart < 0) kstart = 0;
  kstart &= ~31;
  const float scale = 0.08838834764831845f;  // 1/sqrt(128)

  for (int k0 = kstart; k0 <= q0 + 15; k0 += 32) {
    f32x4 sv[2];
    for (int kh = 0; kh < 2; ++kh) {
      f32x4 s = {};
      const u16* krow = Kb + ((size_t)kvh * T_SEQ + (k0 + kh * 16 + l15)) * 128;
      for (int ks = 0; ks < 4; ++ks) {
        bf16x8 kf = *(const bf16x8*)(krow + ks * 32 + l4 * 8);
        s = __builtin_amdgcn_mfma_f32_16x16x32_bf16(qf[ks], kf, s, 0, 0, 0);
      }
      sv[kh] = s;
    }
    // mask + online softmax
    float pv[2][4], sc[4];
    for (int i = 0; i < 4; ++i) {
      int q = q0 + l4 * 4 + i;
      float mx = -3e38f;
      for (int kh = 0; kh < 2; ++kh) {
        int k = k0 + kh * 16 + l15;
        bool ok = ((k >> 2) <= (q >> 2)) && (q - k < WIN);
        float s = ok ? sv[kh][i] * scale : -3e38f;
        pv[kh][i] = s;
        mx = fmaxf(mx, s);
      }
      for (int off = 1; off < 16; off <<= 1)
        mx = fmaxf(mx, __shfl_xor(mx, off));
      float mn = fmaxf(m[i], mx);
      sc[i] = __expf(m[i] - mn);
      m[i] = mn;
      float rsum = 0.f;
      for (int kh = 0; kh < 2; ++kh) {
        float p = __expf(pv[kh][i] - mn);
        pv[kh][i] = p;
        rsum += p;
      }
      for (int off = 1; off < 16; off <<= 1)
        rsum += __shfl_xor(rsum, off);
      lsum[i] = lsum[i] * sc[i] + rsum;
    }
    for (int nt = 0; nt < 8; ++nt)
      for (int i = 0; i < 4; ++i)
        acc[nt][i] *= sc[i];
    // P -> LDS (reshape to A-fragment layout)
    __syncthreads();
    for (int kh = 0; kh < 2; ++kh)
      for (int i = 0; i < 4; ++i)
        p_lds[l4 * 4 + i][kh * 16 + l15] = f2bf(pv[kh][i]);
    __syncthreads();
    bf16x8 pf = *(const bf16x8*)(&p_lds[l15][l4 * 8]);
    for (int nt = 0; nt < 8; ++nt) {
      const u16* vrow = Vt + ((size_t)kvh * 128 + nt * 16 + l15) * T_SEQ + k0 + l4 * 8;
      bf16x8 vf = *(const bf16x8*)vrow;
      acc[nt] = __builtin_amdgcn_mfma_f32_16x16x32_bf16(pf, vf, acc[nt], 0, 0, 0);
    }
  }
  for (int nt = 0; nt < 8; ++nt)
    for (int i = 0; i < 4; ++i) {
      int q = q0 + l4 * 4 + i;
      O[(size_t)q * (NQ * DH) + h * DH + nt * 16 + l15] = f2bf(acc[nt][i] / lsum[i]);
    }
}

extern "C" void kernel_launch(void* const* d_in, const int* in_sizes, int n_in,
                              void* d_out, int out_size, void* d_ws, size_t ws_size,
                              hipStream_t stream) {
  const float* hidden = (const float*)d_in[0];
  const float* cosb   = (const float*)d_in[1];
  const float* sinb   = (const float*)d_in[2];
  const float* w_qkv  = (const float*)d_in[3];
  const float* qnw    = (const float*)d_in[4];
  const float* knw    = (const float*)d_in[5];
  const float* w_o    = (const float*)d_in[6];
  float* out = (float*)d_out;
  char* ws = (char*)d_ws;

  // workspace layout (MB offsets); woT/attn reuse regions freed after gemm1
  u16*   wqkvT  = (u16*)(ws);                     // [0, 48M)
  u16*   hid_bf = (u16*)(ws + ((size_t)48 << 20)); // [48M, 64M)
  float* qkv    = (float*)(ws + ((size_t)64 << 20)); // [64M, 112M)
  u16*   q_bf   = (u16*)(ws + ((size_t)112 << 20)); // 16MB
  u16*   k_bf   = (u16*)(ws + ((size_t)128 << 20)); // 4MB
  u16*   vt_bf  = (u16*)(ws + ((size_t)132 << 20)); // 4MB
  u16*   attn_bf= (u16*)(ws + ((size_t)48 << 20));  // reuse hid_bf region
  u16*   woT    = (u16*)(ws);                       // reuse wqkvT region

  f32_to_bf16<<<4096, 256, 0, stream>>>(hidden, hid_bf, T_SEQ * HID);
  transpose_f32_to_bf16<<<dim3(192, 128), dim3(32, 8), 0, stream>>>(w_qkv, wqkvT, HID, 6144);
  gemm_bt<<<dim3(16, 48), 256, 0, stream>>>(hid_bf, wqkvT, qkv, T_SEQ, 6144, HID);
  transpose_f32_to_bf16<<<dim3(128, 128), dim3(32, 8), 0, stream>>>(w_o, woT, NQ * DH, HID);
  rope_kernel<<<(T_SEQ * 48) / 4, 256, 0, stream>>>(qkv, cosb, sinb, qnw, knw, q_bf, k_bf, vt_bf);
  attn_kernel<<<dim3(T_SEQ / 16, NQ), 64, 0, stream>>>(q_bf, k_bf, vt_bf, attn_bf);
  gemm_bt<<<dim3(16, 32), 256, 0, stream>>>(attn_bf, woT, out, T_SEQ, HID, NQ * DH);
}

// Round 2
// 426.981 us; speedup vs baseline: 1.4710x; 1.4710x over previous
//
#include <hip/hip_runtime.h>
#include <hip/hip_bf16.h>

typedef unsigned short u16;
typedef __attribute__((ext_vector_type(8))) short bf16x8;
typedef __attribute__((ext_vector_type(4))) float f32x4;
typedef __attribute__((ext_vector_type(8))) u16 u16x8;
typedef __attribute__((ext_vector_type(4))) u16 u16x4;

#define T_SEQ 2048
#define HID 4096
#define NQ 32
#define NKV 8
#define DH 128
#define WIN 1024

__device__ __forceinline__ u16 f2bf(float f) {
  union { float f; unsigned int u; } v; v.f = f;
  unsigned int u = v.u;
  unsigned int r = (u + 0x7FFFu + ((u >> 16) & 1u)) >> 16;
  return (u16)r;
}

__device__ __forceinline__ void gload16(const void* g, void* l) {
  __builtin_amdgcn_global_load_lds(
      (const __attribute__((address_space(1))) unsigned int*)g,
      (__attribute__((address_space(3))) unsigned int*)l, 16, 0, 0);
}

// ---------------- elementwise f32 -> bf16 ----------------
__global__ __launch_bounds__(256) void f32_to_bf16(const float* __restrict__ in,
                                                   u16* __restrict__ out, int n) {
  int i = (blockIdx.x * 256 + threadIdx.x) * 8;
  if (i >= n) return;
  float4 a = *(const float4*)(in + i);
  float4 b = *(const float4*)(in + i + 4);
  u16x8 r;
  r[0] = f2bf(a.x); r[1] = f2bf(a.y); r[2] = f2bf(a.z); r[3] = f2bf(a.w);
  r[4] = f2bf(b.x); r[5] = f2bf(b.y); r[6] = f2bf(b.z); r[7] = f2bf(b.w);
  *(u16x8*)(out + i) = r;
}

// ---------------- tiled transpose f32 (R x C) -> bf16 (C x R) ----------------
__global__ __launch_bounds__(256) void transpose_f32_to_bf16(const float* __restrict__ in,
                                                             u16* __restrict__ out,
                                                             int R, int C) {
  __shared__ float tile[32][33];
  int c0 = blockIdx.x * 32, r0 = blockIdx.y * 32;
  int tx = threadIdx.x, ty = threadIdx.y;
  for (int i = 0; i < 32; i += 8)
    tile[ty + i][tx] = in[(size_t)(r0 + ty + i) * C + c0 + tx];
  __syncthreads();
  for (int i = 0; i < 32; i += 8)
    out[(size_t)(c0 + ty + i) * R + r0 + tx] = f2bf(tile[tx][ty + i]);
}

// ---------------- GEMM: C(f32 MxN) = A(bf16 MxK row-major) * Bt(bf16 NxK row-major)^T ----
__global__ __launch_bounds__(256) void gemm_bt(const u16* __restrict__ A,
                                               const u16* __restrict__ Bt,
                                               float* __restrict__ C,
                                               int M, int N, int K) {
  __shared__ u16 lsA[128 * 32];  // 8KB, row-major [128][32]
  __shared__ u16 lsB[128 * 32];
  const int tid = threadIdx.x;
  const int lane = tid & 63, w = tid >> 6;
  const int wr = w >> 1, wc = w & 1;
  const int l15 = lane & 15, l4 = lane >> 4;
  const int bm = blockIdx.x * 128, bn = blockIdx.y * 128;
  f32x4 acc[4][4] = {};

  for (int k0 = 0; k0 < K; k0 += 32) {
    for (int c = 0; c < 2; ++c) {
      int off = c * 4096 + tid * 16;       // byte offset within 8KB tile
      int r = off >> 6, cb = off & 63;     // row, byte-in-row (64B rows)
      gload16(A + (size_t)(bm + r) * K + k0 + (cb >> 1),
              (char*)lsA + c * 4096 + w * 1024);
      gload16(Bt + (size_t)(bn + r) * K + k0 + (cb >> 1),
              (char*)lsB + c * 4096 + w * 1024);
    }
    __syncthreads();
    bf16x8 af[4], bfr[4];
    for (int mt = 0; mt < 4; ++mt) {
      int row = wr * 64 + mt * 16 + l15;
      af[mt] = *(const bf16x8*)(lsA + row * 32 + l4 * 8);
    }
    for (int nt = 0; nt < 4; ++nt) {
      int row = wc * 64 + nt * 16 + l15;
      bfr[nt] = *(const bf16x8*)(lsB + row * 32 + l4 * 8);
    }
    for (int mt = 0; mt < 4; ++mt)
      for (int nt = 0; nt < 4; ++nt)
        acc[mt][nt] = __builtin_amdgcn_mfma_f32_16x16x32_bf16(af[mt], bfr[nt], acc[mt][nt], 0, 0, 0);
    __syncthreads();
  }
  for (int mt = 0; mt < 4; ++mt)
    for (int nt = 0; nt < 4; ++nt) {
      int row = bm + wr * 64 + mt * 16 + l4 * 4;
      int col = bn + wc * 64 + nt * 16 + l15;
      float* p = C + (size_t)row * N + col;
      p[0] = acc[mt][nt][0];
      p[(size_t)N] = acc[mt][nt][1];
      p[2 * (size_t)N] = acc[mt][nt][2];
      p[3 * (size_t)N] = acc[mt][nt][3];
    }
}

// ---------------- RMSNorm + RoPE + layout (Q scaled; Q,K row-major per head; V transposed) -------
__global__ __launch_bounds__(256) void rope_kernel(const float* __restrict__ qkv,
                                                   const float* __restrict__ cosb,
                                                   const float* __restrict__ sinb,
                                                   const float* __restrict__ qw,
                                                   const float* __restrict__ kw,
                                                   u16* __restrict__ Qo,
                                                   u16* __restrict__ Ko,
                                                   u16* __restrict__ Vt) {
  int wid = threadIdx.x >> 6, lane = threadIdx.x & 63;
  int item = blockIdx.x * 4 + wid;          // item = t*48 + hid
  int t = item / 48, hid = item % 48;
  const float* x = qkv + (size_t)t * 6144 + hid * 128;
  float x1 = x[lane], x2 = x[lane + 64];
  if (hid < NQ + NKV) {
    float ss = x1 * x1 + x2 * x2;
    for (int off = 32; off; off >>= 1) ss += __shfl_xor(ss, off);
    float inv = rsqrtf(ss * (1.0f / 128.0f) + 1e-6f);
    const float* wn = (hid < NQ) ? qw : kw;
    float n1 = x1 * inv * wn[lane], n2 = x2 * inv * wn[lane + 64];
    float c1 = cosb[t * 128 + lane], s1 = sinb[t * 128 + lane];
    float c2 = cosb[t * 128 + lane + 64], s2 = sinb[t * 128 + lane + 64];
    float o1 = n1 * c1 - n2 * s1;
    float o2 = n2 * c2 + n1 * s2;
    if (hid < NQ) {
      const float scale = 0.08838834764831845f;  // fold 1/sqrt(128) into Q
      u16* q = Qo + ((size_t)hid * T_SEQ + t) * 128;
      q[lane] = f2bf(o1 * scale); q[lane + 64] = f2bf(o2 * scale);
    } else {
      int h = hid - NQ;
      u16* k = Ko + ((size_t)h * T_SEQ + t) * 128;
      k[lane] = f2bf(o1); k[lane + 64] = f2bf(o2);
    }
  } else {
    int h = hid - (NQ + NKV);
    Vt[((size_t)h * 128 + lane) * T_SEQ + t] = f2bf(x1);
    Vt[((size_t)h * 128 + lane + 64) * T_SEQ + t] = f2bf(x2);
  }
}

#define WAITVM4() asm volatile("s_waitcnt vmcnt(4)" ::: "memory")
#define WAITVM0() asm volatile("s_waitcnt vmcnt(0)" ::: "memory")

// ---------------- flash attention: 4 waves/block, QBLK=64, KBLK=32, LDS dbuf ----------------
__global__ __launch_bounds__(256) void attn_kernel(const u16* __restrict__ Q,
                                                   const u16* __restrict__ Kb,
                                                   const u16* __restrict__ Vt,
                                                   u16* __restrict__ O) {
  __shared__ u16 kls[2][32 * 128];   // swizzled: chunk16 ^= (row&7)
  __shared__ u16 vls[2][128 * 32];   // swizzled: chunk16 ^= ((d>>1)&3)
  __shared__ u16 plds[4][16 * 40];   // per-wave P buffer [16 q][32 k] pad to 40

  const int tid = threadIdx.x;
  const int lane = tid & 63, w = tid >> 6;
  const int l15 = lane & 15, l4 = lane >> 4;
  const int h = blockIdx.x;          // q head
  const int q0 = blockIdx.y * 64;    // block q base
  const int wq0 = q0 + w * 16;       // wave q base
  const int kvh = h >> 2;

  // Q fragments (B operand of swapped QK^T): lane holds Q[wq0+l15][ks*32+l4*8..]
  bf16x8 qf[4];
  {
    const u16* qrow = Q + ((size_t)h * T_SEQ + (wq0 + l15)) * DH;
    for (int ks = 0; ks < 4; ++ks)
      qf[ks] = *(const bf16x8*)(qrow + ks * 32 + l4 * 8);
  }

  f32x4 acc[8] = {};
  float m = -1e30f, lsum = 0.f;

  int ks0 = q0 - (WIN - 1); if (ks0 < 0) ks0 = 0;
  ks0 &= ~31;
  const int kend = q0 + 32;          // last tile start (covers k up to q0+63)

  // ---- staging helper (per wave, 4 gload16: 2 K + 2 V) ----
  auto stage = [&](int b, int k0) {
    for (int c = 0; c < 2; ++c) {
      int base = w * 2048 + c * 1024;            // bytes in 8KB tile
      int idx = base / 16 + lane;                // 16B chunk index
      {
        int row = idx >> 4;                      // K row (32 rows x 256B)
        int col = (idx & 15) ^ (row & 7);        // pre-swizzled source chunk
        gload16(Kb + ((size_t)kvh * T_SEQ + k0 + row) * DH + col * 8,
                (char*)kls[b] + base);
      }
      {
        int d = idx >> 2;                        // V^T row (128 rows x 64B)
        int ch = (idx & 3) ^ ((d >> 1) & 3);
        gload16(Vt + ((size_t)kvh * DH + d) * T_SEQ + k0 + ch * 8,
                (char*)vls[b] + base);
      }
    }
  };

  stage(0, ks0);
  int buf = 0;
  for (int k0 = ks0; k0 <= kend; k0 += 32) {
    bool more = (k0 + 32 <= kend);
    if (more) stage(buf ^ 1, k0 + 32);
    if (more) { WAITVM4(); } else { WAITVM0(); }
    __builtin_amdgcn_s_barrier();
    __builtin_amdgcn_sched_barrier(0);

    // wave-level skip: does this tile intersect [wq0-1023, wq0+15]?
    if (k0 <= wq0 + 15 && k0 + 31 >= wq0 - (WIN - 1)) {
      // ---- QK^T (swapped): S^T[k][q],  A=K from LDS, B=Q regs ----
      f32x4 st[2];
      for (int kh = 0; kh < 2; ++kh) {
        f32x4 s = {};
        int row = kh * 16 + l15;
        const char* kb = (const char*)kls[buf] + row * 256;
        for (int ks = 0; ks < 4; ++ks) {
          int chunk = (ks * 4 + l4) ^ (row & 7);
          bf16x8 kf = *(const bf16x8*)(kb + chunk * 16);
          s = __builtin_amdgcn_mfma_f32_16x16x32_bf16(kf, qf[ks], s, 0, 0, 0);
        }
        st[kh] = s;
      }
      // ---- mask + online softmax (lane owns q = wq0+l15; k = k0+kh*16+l4*4+i) ----
      const int q = wq0 + l15;
      float pv[2][4];
      float mx = -3e38f;
      for (int kh = 0; kh < 2; ++kh)
        for (int i = 0; i < 4; ++i) {
          int k = k0 + kh * 16 + l4 * 4 + i;
          bool ok = ((k >> 2) <= (q >> 2)) && (q - k < WIN);
          float s = ok ? st[kh][i] : -3e38f;
          pv[kh][i] = s;
          mx = fmaxf(mx, s);
        }
      mx = fmaxf(mx, __shfl_xor(mx, 16));
      mx = fmaxf(mx, __shfl_xor(mx, 32));
      if (!__all(mx <= m + 8.f)) {      // defer-max: rescale only on real growth
        float mn = fmaxf(m, mx);
        float sc = __expf(m - mn);
        m = mn;
        lsum *= sc;
        for (int nt = 0; nt < 8; ++nt)
          for (int i = 0; i < 4; ++i) acc[nt][i] *= sc;
      }
      float rs = 0.f;
      for (int kh = 0; kh < 2; ++kh)
        for (int i = 0; i < 4; ++i) {
          float p = __expf(pv[kh][i] - m);
          pv[kh][i] = p;
          rs += p;
        }
      rs += __shfl_xor(rs, 16);
      rs += __shfl_xor(rs, 32);
      lsum += rs;
      // ---- pack P -> per-wave LDS [q][k] ----
      u16* pw = plds[w];
      for (int kh = 0; kh < 2; ++kh) {
        unsigned int d0 = (unsigned int)f2bf(pv[kh][0]) | ((unsigned int)f2bf(pv[kh][1]) << 16);
        unsigned int d1 = (unsigned int)f2bf(pv[kh][2]) | ((unsigned int)f2bf(pv[kh][3]) << 16);
        *(unsigned int*)(pw + l15 * 40 + kh * 16 + l4 * 4) = d0;
        *(unsigned int*)(pw + l15 * 40 + kh * 16 + l4 * 4 + 2) = d1;
      }
      bf16x8 pf = *(const bf16x8*)(pw + l15 * 40 + l4 * 8);
      // ---- PV: O^T += V^T * P^T  (A = V^T from LDS, B = P) ----
      for (int nt = 0; nt < 8; ++nt) {
        int d = nt * 16 + l15;
        int chunk = l4 ^ ((d >> 1) & 3);
        bf16x8 vf = *(const bf16x8*)((const char*)vls[buf] + d * 64 + chunk * 16);
        acc[nt] = __builtin_amdgcn_mfma_f32_16x16x32_bf16(vf, pf, acc[nt], 0, 0, 0);
      }
    }
    __builtin_amdgcn_sched_barrier(0);
    __builtin_amdgcn_s_barrier();
    buf ^= 1;
  }

  // ---- epilogue: O[q][h*128 + d], acc[nt][i] = O^T[nt*16+l4*4+i][l15] ----
  float inv = 1.0f / lsum;
  for (int nt = 0; nt < 8; ++nt) {
    u16x4 o;
    for (int i = 0; i < 4; ++i) o[i] = f2bf(acc[nt][i] * inv);
    *(u16x4*)(O + (size_t)(wq0 + l15) * (NQ * DH) + h * DH + nt * 16 + l4 * 4) = o;
  }
}

extern "C" void kernel_launch(void* const* d_in, const int* in_sizes, int n_in,
                              void* d_out, int out_size, void* d_ws, size_t ws_size,
                              hipStream_t stream) {
  const float* hidden = (const float*)d_in[0];
  const float* cosb   = (const float*)d_in[1];
  const float* sinb   = (const float*)d_in[2];
  const float* w_qkv  = (const float*)d_in[3];
  const float* qnw    = (const float*)d_in[4];
  const float* knw    = (const float*)d_in[5];
  const float* w_o    = (const float*)d_in[6];
  float* out = (float*)d_out;
  char* ws = (char*)d_ws;

  u16*   wqkvT  = (u16*)(ws);                      // [0, 48M)
  u16*   hid_bf = (u16*)(ws + ((size_t)48 << 20)); // [48M, 64M)
  float* qkv    = (float*)(ws + ((size_t)64 << 20)); // [64M, 112M)
  u16*   q_bf   = (u16*)(ws + ((size_t)112 << 20)); // 16MB
  u16*   k_bf   = (u16*)(ws + ((size_t)128 << 20)); // 4MB
  u16*   vt_bf  = (u16*)(ws + ((size_t)132 << 20)); // 4MB
  u16*   attn_bf= (u16*)(ws + ((size_t)48 << 20));  // reuse hid_bf region
  u16*   woT    = (u16*)(ws);                       // reuse wqkvT region

  f32_to_bf16<<<4096, 256, 0, stream>>>(hidden, hid_bf, T_SEQ * HID);
  transpose_f32_to_bf16<<<dim3(192, 128), dim3(32, 8), 0, stream>>>(w_qkv, wqkvT, HID, 6144);
  gemm_bt<<<dim3(16, 48), 256, 0, stream>>>(hid_bf, wqkvT, qkv, T_SEQ, 6144, HID);
  transpose_f32_to_bf16<<<dim3(128, 128), dim3(32, 8), 0, stream>>>(w_o, woT, NQ * DH, HID);
  rope_kernel<<<(T_SEQ * 48) / 4, 256, 0, stream>>>(qkv, cosb, sinb, qnw, knw, q_bf, k_bf, vt_bf);
  attn_kernel<<<dim3(NQ, T_SEQ / 64), 256, 0, stream>>>(q_bf, k_bf, vt_bf, attn_bf);
  gemm_bt<<<dim3(16, 32), 256, 0, stream>>>(attn_bf, woT, out, T_SEQ, HID, NQ * DH);
}